// Round 4
// baseline (327.919 us; speedup 1.0000x reference)
//
#include <hip/hip_runtime.h>
#include <hip/hip_bf16.h>

typedef __bf16 bf16_t;
typedef __attribute__((ext_vector_type(8))) __bf16 bf16x8;
typedef __attribute__((ext_vector_type(4))) __bf16 bf16x4;
typedef __attribute__((ext_vector_type(4))) float floatx4;

#define NB 8192   // rows of x (B)
#define NC 8192   // rows of y (C)
#define ND 256    // feature dim D
#define NKT 8     // k-tiles of 32
#define BM 128
#define BN 128

// ---------------------------------------------------------------------------
// prep: fp32 -> bf16 in MFMA-FRAGMENT-SWIZZLED layout + row norms.
// Swizzle: for 16-row group g, k-tile kt, the 1 KB block at
//   ((g*NKT + kt) << 10)  holds row rr (0..15), k-chunk q (0..3, 8 bf16)
//   at byte offset q*256 + rr*16, element k = q*8 + j at +j*2.
// A GEMM wave then loads its whole 16x32 fragment with ONE coalesced
// global_load_dwordx4 at block_base + lane*16 (lane = rr + 16*q, matching
// the mfma_f32_16x16x32_bf16 A/B operand layout A[m=lane&15][k=quad*8+j]).
// One wave per row; lane l converts elements [l*4, l*4+4)  (64*4 = 256 ✓)
// and writes an 8-byte half-chunk: kt=l>>3, q=(l>>1)&3, +(l&1)*8.
// ---------------------------------------------------------------------------
__global__ __launch_bounds__(256) void prep_kernel(
    const float* __restrict__ x, const float* __restrict__ y,
    bf16_t* __restrict__ xs, bf16_t* __restrict__ ys,
    float* __restrict__ x2, float* __restrict__ y2)
{
    int t    = threadIdx.x;
    int wave = t >> 6;
    int lane = t & 63;
    int row  = blockIdx.x * 4 + wave;   // 0..16383 (x rows then y rows)

    const float* src;
    bf16_t* dst;
    float* nrm;
    int r;
    if (row < NB) { src = x; dst = xs; nrm = x2; r = row; }
    else          { src = y; dst = ys; nrm = y2; r = row - NB; }

    float4 v = ((const float4*)(src + (size_t)r * ND))[lane];
    float ss = v.x * v.x + v.y * v.y + v.z * v.z + v.w * v.w;

    bf16x4 o;
    o.x = (__bf16)v.x; o.y = (__bf16)v.y; o.z = (__bf16)v.z; o.w = (__bf16)v.w;

    const int g  = r >> 4;          // 16-row group
    const int rr = r & 15;
    const int kt = lane >> 3;       // 0..7  ✓ (32 elems per k-tile)
    const int q  = (lane >> 1) & 3; // 8-elem k-chunk within the tile
    const int h  = (lane & 1) * 8;  // half-chunk byte offset
    char* p = (char*)dst + (((size_t)(g * NKT + kt)) << 10) + q * 256 + rr * 16 + h;
    *(bf16x4*)p = o;

    #pragma unroll
    for (int off = 32; off >= 1; off >>= 1)
        ss += __shfl_xor(ss, off, 64);
    if (lane == 0) nrm[r] = ss;
}

// ---------------------------------------------------------------------------
// RBF GEMM, LDS-free: out[b,c] = exp(-gamma * max(x2[b]+y2[c]-2*dot, 0)).
// 128x128 block, 4 waves (2x2), each wave 64x64 = 4x4 MFMA 16x16x32 bf16.
// Fragments load DIRECTLY from the swizzled global panels (one coalesced
// dwordx4 per fragment per lane), register-double-buffered over kt. No LDS,
// no barriers -> loads pipeline freely against MFMA. Panels (8 MB total)
// are L2/L3 resident. Output stores are nontemporal to keep the 268 MB
// write stream from evicting the panels out of L2.
// ---------------------------------------------------------------------------
__global__ __launch_bounds__(256) void rbf_gemm_kernel(
    const bf16_t* __restrict__ xs, const bf16_t* __restrict__ ys,
    const float* __restrict__ x2, const float* __restrict__ y2,
    const float* __restrict__ gamma_p, float* __restrict__ out)
{
    const int t    = threadIdx.x;
    const int lane = t & 63;
    const int wave = t >> 6;
    const int wm   = wave >> 1;      // 0..1
    const int wn   = wave & 1;       // 0..1
    const int quad = lane >> 4;      // 0..3
    const int l15  = lane & 15;

    const int bm = blockIdx.x * BM;
    const int bn = blockIdx.y * BN;

    const float gamma = *gamma_p;

    floatx4 acc[4][4];
    #pragma unroll
    for (int i = 0; i < 4; ++i)
        #pragma unroll
        for (int j = 0; j < 4; ++j)
            acc[i][j] = (floatx4){0.f, 0.f, 0.f, 0.f};

    // Fragment base addresses (this lane's 16 B within each 1 KB block).
    // A fragment (i, kt): group g = bm/16 + wm*4 + i  ->  +i*8 KB, +kt*1 KB.
    const char* aBase = (const char*)xs
        + (((size_t)((bm >> 4) + wm * 4) * NKT) << 10) + (size_t)lane * 16;
    const char* bBase = (const char*)ys
        + (((size_t)((bn >> 4) + wn * 4) * NKT) << 10) + (size_t)lane * 16;

    bf16x8 af[2][4], bfv[2][4];
    auto ldset = [&](int kt, int buf) {
        #pragma unroll
        for (int i = 0; i < 4; ++i) {
            af[buf][i]  = *(const bf16x8*)(aBase + i * (NKT * 1024) + kt * 1024);
            bfv[buf][i] = *(const bf16x8*)(bBase + i * (NKT * 1024) + kt * 1024);
        }
    };

    ldset(0, 0);
    #pragma unroll
    for (int kt = 0; kt < NKT; ++kt) {
        const int cb = kt & 1;
        if (kt + 1 < NKT) ldset(kt + 1, cb ^ 1);
        #pragma unroll
        for (int i = 0; i < 4; ++i)
            #pragma unroll
            for (int j = 0; j < 4; ++j)
                acc[i][j] = __builtin_amdgcn_mfma_f32_16x16x32_bf16(
                    af[cb][i], bfv[cb][j], acc[i][j], 0, 0, 0);
    }

    // Epilogue. C/D layout: col = lane&15, row = quad*4 + reg  [m89/m91].
    #pragma unroll
    for (int i = 0; i < 4; ++i) {
        const int grow0 = bm + wm * 64 + i * 16 + quad * 4;   // 4-aligned
        const float4 xn = *(const float4*)(x2 + grow0);
        #pragma unroll
        for (int j = 0; j < 4; ++j) {
            const int gcol = bn + wn * 64 + j * 16 + l15;
            const float yn = y2[gcol];
            float* op = out + (size_t)grow0 * NC + gcol;
            const float xr[4] = {xn.x, xn.y, xn.z, xn.w};
            #pragma unroll
            for (int r = 0; r < 4; ++r) {
                float sq = xr[r] + yn - 2.0f * acc[i][j][r];
                sq = fmaxf(sq, 0.0f);
                __builtin_nontemporal_store(__expf(-gamma * sq),
                                            op + (size_t)r * NC);
            }
        }
    }
}

extern "C" void kernel_launch(void* const* d_in, const int* in_sizes, int n_in,
                              void* d_out, int out_size, void* d_ws, size_t ws_size,
                              hipStream_t stream) {
    const float* x = (const float*)d_in[0];
    const float* y = (const float*)d_in[1];
    const float* gamma = (const float*)d_in[2];
    float* out = (float*)d_out;

    // Workspace layout: xs (4 MB) | ys (4 MB) | x2 (32 KB) | y2 (32 KB)
    bf16_t* xs = (bf16_t*)d_ws;
    bf16_t* ys = xs + (size_t)NB * ND;
    float*  x2 = (float*)(ys + (size_t)NC * ND);
    float*  y2 = x2 + NB;

    prep_kernel<<<dim3((NB + NC) / 4), dim3(256), 0, stream>>>(x, y, xs, ys, x2, y2);
    rbf_gemm_kernel<<<dim3(NB / BM, NC / BN), dim3(256), 0, stream>>>(
        xs, ys, x2, y2, gamma, out);
}

// Round 6
// 315.520 us; speedup vs baseline: 1.0393x; 1.0393x over previous
//
#include <hip/hip_runtime.h>
#include <hip/hip_bf16.h>

typedef __bf16 bf16_t;
typedef __attribute__((ext_vector_type(8))) __bf16 bf16x8;
typedef __attribute__((ext_vector_type(4))) __bf16 bf16x4;
typedef __attribute__((ext_vector_type(4))) float floatx4;

#define NB 8192   // rows of x (B)
#define NC 8192   // rows of y (C)
#define ND 256    // feature dim D
#define NKT 8     // k-tiles of 32
#define BM 128
#define BN 128

// ---------------------------------------------------------------------------
// prep: fp32 -> bf16 in MFMA-FRAGMENT-SWIZZLED layout + row norms.
// For 16-row group g, k-tile kt: 1 KB block at ((g*NKT+kt)<<10) holds row rr,
// k-chunk q (8 bf16) at byte q*256 + rr*16. GEMM lane load addr = base+lane*16
// (lane = rr + 16*q matches mfma_16x16x32_bf16 A/B layout).
// One wave per row; lane l converts elements [l*4, l*4+4).
// ---------------------------------------------------------------------------
__global__ __launch_bounds__(256) void prep_kernel(
    const float* __restrict__ x, const float* __restrict__ y,
    bf16_t* __restrict__ xs, bf16_t* __restrict__ ys,
    float* __restrict__ x2, float* __restrict__ y2)
{
    int t    = threadIdx.x;
    int wave = t >> 6;
    int lane = t & 63;
    int row  = blockIdx.x * 4 + wave;   // 0..16383 (x rows then y rows)

    const float* src;
    bf16_t* dst;
    float* nrm;
    int r;
    if (row < NB) { src = x; dst = xs; nrm = x2; r = row; }
    else          { src = y; dst = ys; nrm = y2; r = row - NB; }

    float4 v = ((const float4*)(src + (size_t)r * ND))[lane];
    float ss = v.x * v.x + v.y * v.y + v.z * v.z + v.w * v.w;

    bf16x4 o;
    o.x = (__bf16)v.x; o.y = (__bf16)v.y; o.z = (__bf16)v.z; o.w = (__bf16)v.w;

    const int g  = r >> 4;
    const int rr = r & 15;
    const int kt = lane >> 3;       // 0..7
    const int q  = (lane >> 1) & 3;
    const int h  = (lane & 1) * 8;
    char* p = (char*)dst + (((size_t)(g * NKT + kt)) << 10) + q * 256 + rr * 16 + h;
    *(bf16x4*)p = o;

    #pragma unroll
    for (int off = 32; off >= 1; off >>= 1)
        ss += __shfl_xor(ss, off, 64);
    if (lane == 0) nrm[r] = ss;
}

// ---------------------------------------------------------------------------
// RBF GEMM, LDS-staging-free mainloop + LDS-transpose epilogue.
// 128x128 block, 4 waves (2x2), each wave 64x64 = 4x4 MFMA 16x16x32 bf16.
// Fragments load directly from swizzled global panels (one dwordx4/lane),
// register double-buffered; no barriers anywhere.
// XCD swizzle: xcd = fid&7 owns a 16x32 block cluster -> A slice 1 MB +
// B slice 2 MB fit the 4 MiB per-XCD L2.
// Epilogue: exp in C-layout, transpose via wave-private LDS slice, store
// floatx4/lane -> each store instr = 4 x 256 B contiguous segments,
// nontemporal (bypass L2, protect panels).
// ---------------------------------------------------------------------------
__global__ __launch_bounds__(256) void rbf_gemm_kernel(
    const bf16_t* __restrict__ xs, const bf16_t* __restrict__ ys,
    const float* __restrict__ x2, const float* __restrict__ y2,
    const float* __restrict__ gamma_p, float* __restrict__ out)
{
    __shared__ float et[4][16][68];   // per-wave 16x64 transpose slice (+pad)

    const int t    = threadIdx.x;
    const int lane = t & 63;
    const int wave = t >> 6;
    const int wm   = wave >> 1;
    const int wn   = wave & 1;
    const int quad = lane >> 4;
    const int l15  = lane & 15;

    // XCD-aware block swizzle (heuristic xcd = fid % 8).
    const int fid = blockIdx.x;
    const int xcd = fid & 7;
    const int lid = fid >> 3;
    const int sr  = xcd >> 1;           // 0..3 supercluster row
    const int sc  = xcd & 1;            // 0..1 supercluster col
    const int cr  = lid >> 5;           // 0..15 cluster row
    const int cc  = lid & 31;           // 0..31 cluster col
    const int bm  = (sr * 16 + cr) * BM;
    const int bn  = (sc * 32 + cc) * BN;

    const float gamma = *gamma_p;

    floatx4 acc[4][4];
    #pragma unroll
    for (int i = 0; i < 4; ++i)
        #pragma unroll
        for (int j = 0; j < 4; ++j)
            acc[i][j] = (floatx4){0.f, 0.f, 0.f, 0.f};

    const char* aBase = (const char*)xs
        + (((size_t)((bm >> 4) + wm * 4) * NKT) << 10) + (size_t)lane * 16;
    const char* bBase = (const char*)ys
        + (((size_t)((bn >> 4) + wn * 4) * NKT) << 10) + (size_t)lane * 16;

    bf16x8 af[2][4], bfv[2][4];
    auto ldset = [&](int kt, int buf) {
        #pragma unroll
        for (int i = 0; i < 4; ++i) {
            af[buf][i]  = *(const bf16x8*)(aBase + i * (NKT * 1024) + kt * 1024);
            bfv[buf][i] = *(const bf16x8*)(bBase + i * (NKT * 1024) + kt * 1024);
        }
    };

    ldset(0, 0);
    #pragma unroll
    for (int kt = 0; kt < NKT; ++kt) {
        const int cb = kt & 1;
        if (kt + 1 < NKT) ldset(kt + 1, cb ^ 1);
        #pragma unroll
        for (int i = 0; i < 4; ++i)
            #pragma unroll
            for (int j = 0; j < 4; ++j)
                acc[i][j] = __builtin_amdgcn_mfma_f32_16x16x32_bf16(
                    af[cb][i], bfv[cb][j], acc[i][j], 0, 0, 0);
    }

    // Epilogue. C/D layout: col = lane&15, row = quad*4 + reg  [m89/m91].
    float (*ew)[68] = et[wave];
    const int colbase = bn + wn * 64;
    #pragma unroll
    for (int i = 0; i < 4; ++i) {
        const int grow0 = bm + wm * 64 + i * 16;
        const float4 xn = *(const float4*)(x2 + grow0 + quad * 4);
        const float xr[4] = {xn.x, xn.y, xn.z, xn.w};
        #pragma unroll
        for (int j = 0; j < 4; ++j) {
            const float yn = y2[colbase + j * 16 + l15];
            #pragma unroll
            for (int r = 0; r < 4; ++r) {
                float sq = xr[r] + yn - 2.0f * acc[i][j][r];
                sq = fmaxf(sq, 0.0f);
                ew[quad * 4 + r][j * 16 + l15] = __expf(-gamma * sq);
            }
        }
        // Same-wave LDS round-trip: compiler inserts lgkmcnt wait; no barrier.
        #pragma unroll
        for (int c = 0; c < 4; ++c) {
            const int rr = c * 4 + quad;          // 0..15
            floatx4 v = *(const floatx4*)&ew[rr][l15 * 4];
            __builtin_nontemporal_store(
                v, (floatx4*)(out + (size_t)(grow0 + rr) * NC + colbase + l15 * 4));
        }
    }
}

extern "C" void kernel_launch(void* const* d_in, const int* in_sizes, int n_in,
                              void* d_out, int out_size, void* d_ws, size_t ws_size,
                              hipStream_t stream) {
    const float* x = (const float*)d_in[0];
    const float* y = (const float*)d_in[1];
    const float* gamma = (const float*)d_in[2];
    float* out = (float*)d_out;

    // Workspace layout: xs (4 MB) | ys (4 MB) | x2 (32 KB) | y2 (32 KB)
    bf16_t* xs = (bf16_t*)d_ws;
    bf16_t* ys = xs + (size_t)NB * ND;
    float*  x2 = (float*)(ys + (size_t)NC * ND);
    float*  y2 = x2 + NB;

    prep_kernel<<<dim3((NB + NC) / 4), dim3(256), 0, stream>>>(x, y, xs, ys, x2, y2);
    rbf_gemm_kernel<<<dim3((NB / BM) * (NC / BN)), dim3(256), 0, stream>>>(
        xs, ys, x2, y2, gamma, out);
}